// Round 1
// baseline (351.252 us; speedup 1.0000x reference)
//
#include <hip/hip_runtime.h>

typedef unsigned short u16;
typedef unsigned int u32;
typedef __bf16 v8bf __attribute__((ext_vector_type(8)));
typedef float v4f __attribute__((ext_vector_type(4)));

#define DEV __device__ __forceinline__

constexpr int CB = 4;     // batch
constexpr int C = 256;    // channels
constexpr int NN = 4096;  // voxels

DEV u16 f2bf(float f) {
  union { float f; u32 u; } v; v.f = f;
  u32 r = v.u + 0x7fffu + ((v.u >> 16) & 1u);  // RNE
  return (u16)(r >> 16);
}

// ---------- transpose + bf16 convert: xT[b][n][c] = bf16(x[b][c][n]) ----------
__global__ __launch_bounds__(256) void k_transpose(const float* __restrict__ x,
                                                   u16* __restrict__ xT) {
  __shared__ float tile[32][33];
  int b = blockIdx.z;
  int n0 = blockIdx.x * 32, c0 = blockIdx.y * 32;
  int tx = threadIdx.x & 31, ty = threadIdx.x >> 5;  // 32 x 8
  const float* xb = x + (long)b * C * NN;
#pragma unroll
  for (int r = 0; r < 4; ++r)
    tile[ty + r * 8][tx] = xb[(long)(c0 + ty + r * 8) * NN + n0 + tx];
  __syncthreads();
  u16* xTb = xT + (long)b * NN * C;
#pragma unroll
  for (int r = 0; r < 4; ++r)
    xTb[(long)(n0 + ty + r * 8) * C + c0 + tx] = f2bf(tile[tx][ty + r * 8]);
}

// ---------- fp32 -> bf16 convert (weights) ----------
__global__ __launch_bounds__(256) void k_cvt(const float* __restrict__ src,
                                             u16* __restrict__ dst, int n) {
  int i = blockIdx.x * 256 + threadIdx.x;
  if (i < n) dst[i] = f2bf(src[i]);
}

// stage 64 rows x 256 u16 (global row stride 256) into LDS rows of 264 (pad 8)
DEV void stage_tile(const u16* __restrict__ g, u16* lds, int t) {
#pragma unroll
  for (int i = 0; i < 8; ++i) {
    int id = t + i * 256;
    int row = id >> 5, ch = id & 31;
    *reinterpret_cast<float4*>(lds + row * 264 + ch * 8) =
        *reinterpret_cast<const float4*>(g + row * 256 + ch * 8);
  }
}

// ---------- generic C[m,n'] = scale*(sum_k A[m,k]B[n',k] + bias) (+resid) ----------
// A: (M x 256) bf16 rows, B: (N' x 256) bf16 rows. 64x64 tile per block, K=256.
__global__ __launch_bounds__(256) void k_gemm(
    const u16* __restrict__ A, long aStr, const u16* __restrict__ Bm, long bStr,
    const float* __restrict__ biasM, const float* __restrict__ biasN,
    const float* __restrict__ resid, long rStr, float scale,
    float* __restrict__ outF, u16* __restrict__ outH, long oStr, int ldm, int ldn) {
  __shared__ __align__(16) u16 Ash[64 * 264];
  __shared__ __align__(16) u16 Bsh[64 * 264];
  int t = threadIdx.x;
  int w = t >> 6, lane = t & 63, lr = lane & 15, q = lane >> 4;
  int m0 = blockIdx.x * 64, n0 = blockIdx.y * 64, b = blockIdx.z;
  stage_tile(A + b * aStr + (long)m0 * 256, Ash, t);
  stage_tile(Bm + b * bStr + (long)n0 * 256, Bsh, t);
  __syncthreads();
  v4f acc[4];
#pragma unroll
  for (int nt = 0; nt < 4; ++nt)
#pragma unroll
    for (int r = 0; r < 4; ++r) acc[nt][r] = 0.f;
#pragma unroll
  for (int ks = 0; ks < 8; ++ks) {
    v8bf a = *reinterpret_cast<const v8bf*>(Ash + (w * 16 + lr) * 264 + ks * 32 + q * 8);
#pragma unroll
    for (int nt = 0; nt < 4; ++nt) {
      v8bf bb = *reinterpret_cast<const v8bf*>(Bsh + (nt * 16 + lr) * 264 + ks * 32 + q * 8);
      acc[nt] = __builtin_amdgcn_mfma_f32_16x16x32_bf16(a, bb, acc[nt], 0, 0, 0);
    }
  }
#pragma unroll
  for (int nt = 0; nt < 4; ++nt) {
#pragma unroll
    for (int r = 0; r < 4; ++r) {
      int gm = m0 + w * 16 + q * 4 + r;   // D row
      int gn = n0 + nt * 16 + lr;         // D col
      float val = acc[nt][r];
      if (biasM) val += biasM[gm];
      if (biasN) val += biasN[gn];
      val *= scale;
      long addr = b * oStr + (long)gm * ldm + (long)gn * ldn;
      if (resid) val += resid[b * rStr + (long)gm * ldm + (long)gn * ldn];
      if (outF) outF[addr] = val;
      else outH[addr] = f2bf(val);
    }
  }
}

// ---------- flash attention: O[b][i][c] = sum_j softmax_j(q.k)[i,j] * v[c,j] ----------
// qT,kT: (B,N,C) bf16 (q pre-scaled by 1/16); V: (B,C,N) bf16; O: (B,N,C) bf16
__global__ __launch_bounds__(256) void k_flash(const u16* __restrict__ qT,
                                               const u16* __restrict__ kT,
                                               const u16* __restrict__ V,
                                               u16* __restrict__ O) {
  __shared__ __align__(16) u16 ksh[64 * 264];   // 64 j-rows x 256 c (+8 pad)
  __shared__ __align__(16) u16 vsh[256 * 72];   // 256 c-rows x 64 j (+8 pad)
  __shared__ __align__(16) u16 psh[4 * 16 * 72];  // per-wave 16 i x 64 j (+8 pad)
  int t = threadIdx.x;
  int w = t >> 6, lane = t & 63, lr = lane & 15, q = lane >> 4;
  int b = blockIdx.y;
  int i0 = blockIdx.x * 64;
  const u16* qb = qT + ((long)b * NN + i0 + w * 16) * C;
  const u16* kb = kT + (long)b * NN * C;
  const u16* vb = V + (long)b * C * NN;

  v8bf qf[8];  // Q rows for this wave, A-fragment layout, held in regs
#pragma unroll
  for (int ks = 0; ks < 8; ++ks)
    qf[ks] = *reinterpret_cast<const v8bf*>(qb + lr * C + ks * 32 + q * 8);

  v4f accO[16];
#pragma unroll
  for (int ct = 0; ct < 16; ++ct)
#pragma unroll
    for (int r = 0; r < 4; ++r) accO[ct][r] = 0.f;
  float mst[4], lst[4];
#pragma unroll
  for (int r = 0; r < 4; ++r) { mst[r] = -3.0e38f; lst[r] = 0.f; }

  u16* pw = psh + w * (16 * 72);

  for (int j0 = 0; j0 < NN; j0 += 64) {
    __syncthreads();  // previous iter's LDS reads done before overwrite
    // stage K tile: 64 rows (j) x 256 c
#pragma unroll
    for (int i = 0; i < 8; ++i) {
      int id = t + i * 256;
      int row = id >> 5, ch = id & 31;
      *reinterpret_cast<float4*>(ksh + row * 264 + ch * 8) =
          *reinterpret_cast<const float4*>(kb + (long)(j0 + row) * C + ch * 8);
    }
    // stage V tile: 256 rows (c) x 64 j
#pragma unroll
    for (int i = 0; i < 8; ++i) {
      int id = t + i * 256;
      int row = id >> 3, ch = id & 7;
      *reinterpret_cast<float4*>(vsh + row * 72 + ch * 8) =
          *reinterpret_cast<const float4*>(vb + (long)row * NN + j0 + ch * 8);
    }
    __syncthreads();

    // S[i, j0+jt*16+col] = qT . k   (scale already folded into q)
    v4f s[4];
#pragma unroll
    for (int jt = 0; jt < 4; ++jt)
#pragma unroll
      for (int r = 0; r < 4; ++r) s[jt][r] = 0.f;
#pragma unroll
    for (int ks = 0; ks < 8; ++ks) {
#pragma unroll
      for (int jt = 0; jt < 4; ++jt) {
        v8bf kf = *reinterpret_cast<const v8bf*>(ksh + (jt * 16 + lr) * 264 + ks * 32 + q * 8);
        s[jt] = __builtin_amdgcn_mfma_f32_16x16x32_bf16(qf[ks], kf, s[jt], 0, 0, 0);
      }
    }

    // online softmax; rows of this lane: i = q*4 + r; row-group = 16 lanes sharing q
    float al[4];
#pragma unroll
    for (int r = 0; r < 4; ++r) {
      float mx = fmaxf(fmaxf(s[0][r], s[1][r]), fmaxf(s[2][r], s[3][r]));
#pragma unroll
      for (int d = 1; d < 16; d <<= 1) mx = fmaxf(mx, __shfl_xor(mx, d, 64));
      float mn = fmaxf(mst[r], mx);
      al[r] = __expf(mst[r] - mn);
      mst[r] = mn;
    }
#pragma unroll
    for (int r = 0; r < 4; ++r) {
      float rs = 0.f;
#pragma unroll
      for (int jt = 0; jt < 4; ++jt) {
        float p = __expf(s[jt][r] - mst[r]);
        s[jt][r] = p;
        rs += p;
      }
#pragma unroll
      for (int d = 1; d < 16; d <<= 1) rs += __shfl_xor(rs, d, 64);
      lst[r] = lst[r] * al[r] + rs;
    }
#pragma unroll
    for (int ct = 0; ct < 16; ++ct)
#pragma unroll
      for (int r = 0; r < 4; ++r) accO[ct][r] *= al[r];

    // P: C/D layout -> LDS -> A layout (per-wave region)
#pragma unroll
    for (int jt = 0; jt < 4; ++jt)
#pragma unroll
      for (int r = 0; r < 4; ++r)
        pw[(q * 4 + r) * 72 + jt * 16 + lr] = f2bf(s[jt][r]);
    __syncthreads();  // cross-lane LDS RAW needs a real barrier/waitcnt

    v8bf pa0 = *reinterpret_cast<const v8bf*>(pw + lr * 72 + q * 8);
    v8bf pa1 = *reinterpret_cast<const v8bf*>(pw + lr * 72 + 32 + q * 8);
#pragma unroll
    for (int ct = 0; ct < 16; ++ct) {
      v8bf v0 = *reinterpret_cast<const v8bf*>(vsh + (ct * 16 + lr) * 72 + q * 8);
      accO[ct] = __builtin_amdgcn_mfma_f32_16x16x32_bf16(pa0, v0, accO[ct], 0, 0, 0);
      v8bf v1 = *reinterpret_cast<const v8bf*>(vsh + (ct * 16 + lr) * 72 + 32 + q * 8);
      accO[ct] = __builtin_amdgcn_mfma_f32_16x16x32_bf16(pa1, v1, accO[ct], 0, 0, 0);
    }
  }

  float inv[4];
#pragma unroll
  for (int r = 0; r < 4; ++r) inv[r] = 1.0f / lst[r];
  u16* ob = O + ((long)b * NN + i0 + w * 16) * C;
#pragma unroll
  for (int ct = 0; ct < 16; ++ct)
#pragma unroll
    for (int r = 0; r < 4; ++r)
      ob[(q * 4 + r) * C + ct * 16 + lr] = f2bf(accO[ct][r] * inv[r]);
}

extern "C" void kernel_launch(void* const* d_in, const int* in_sizes, int n_in,
                              void* d_out, int out_size, void* d_ws, size_t ws_size,
                              hipStream_t stream) {
  const float* x = (const float*)d_in[0];
  const float* wq = (const float*)d_in[1];
  const float* bq = (const float*)d_in[2];
  const float* wk = (const float*)d_in[3];
  const float* bk = (const float*)d_in[4];
  const float* wv = (const float*)d_in[5];
  const float* bv = (const float*)d_in[6];
  const float* wp = (const float*)d_in[7];
  const float* bp = (const float*)d_in[8];
  float* out = (float*)d_out;
  char* ws = (char*)d_ws;

  // workspace layout (bytes): 4 weights bf16 (128KB each), then 5 x (B,N,C) bf16 8MB
  u16* wqb = (u16*)(ws + 0);
  u16* wkb = (u16*)(ws + 131072L);
  u16* wvb = (u16*)(ws + 262144L);
  u16* wpb = (u16*)(ws + 393216L);
  u16* xT = (u16*)(ws + 524288L);
  u16* qTw = (u16*)(ws + 524288L + 1 * 8388608L);
  u16* kTw = (u16*)(ws + 524288L + 2 * 8388608L);
  u16* vw = (u16*)(ws + 524288L + 3 * 8388608L);
  u16* oW = (u16*)(ws + 524288L + 4 * 8388608L);

  k_cvt<<<256, 256, 0, stream>>>(wq, wqb, 65536);
  k_cvt<<<256, 256, 0, stream>>>(wk, wkb, 65536);
  k_cvt<<<256, 256, 0, stream>>>(wv, wvb, 65536);
  k_cvt<<<256, 256, 0, stream>>>(wp, wpb, 65536);
  k_transpose<<<dim3(128, 8, CB), 256, 0, stream>>>(x, xT);

  long nc = (long)NN * C;
  // qT[n][o] = (xT . wq^T + bq) * C^-0.5 ; kT[n][o]; v[o][n]
  k_gemm<<<dim3(64, 4, CB), 256, 0, stream>>>(xT, nc, wqb, 0, nullptr, bq, nullptr, 0,
                                              0.0625f, nullptr, qTw, nc, C, 1);
  k_gemm<<<dim3(64, 4, CB), 256, 0, stream>>>(xT, nc, wkb, 0, nullptr, bk, nullptr, 0,
                                              1.0f, nullptr, kTw, nc, C, 1);
  k_gemm<<<dim3(64, 4, CB), 256, 0, stream>>>(xT, nc, wvb, 0, nullptr, bv, nullptr, 0,
                                              1.0f, nullptr, vw, nc, 1, NN);
  k_flash<<<dim3(64, CB), 256, 0, stream>>>(qTw, kTw, vw, oW);
  // out[b][o][n] = wp . attn + bp + x
  k_gemm<<<dim3(4, 64, CB), 256, 0, stream>>>(wpb, 0, oW, nc, bp, nullptr, x, nc,
                                              1.0f, out, nullptr, nc, NN, 1);
}

// Round 2
// 337.962 us; speedup vs baseline: 1.0393x; 1.0393x over previous
//
#include <hip/hip_runtime.h>

typedef unsigned short u16;
typedef unsigned int u32;
typedef __bf16 v8bf __attribute__((ext_vector_type(8)));
typedef float v4f __attribute__((ext_vector_type(4)));

#define DEV __device__ __forceinline__

constexpr int CB = 4;     // batch
constexpr int C = 256;    // channels
constexpr int NN = 4096;  // voxels
constexpr float LOG2E = 1.4426950408889634f;

DEV u16 f2bf(float f) {
  union { float f; u32 u; } v; v.f = f;
  u32 r = v.u + 0x7fffu + ((v.u >> 16) & 1u);  // RNE
  return (u16)(r >> 16);
}
DEV float bf2f(u16 h) {
  union { u32 u; float f; } v; v.u = ((u32)h) << 16; return v.f;
}

// async global->LDS DMA, 16B per lane. lds dest must be wave-uniform base;
// HW writes base + lane*16. Casts via integer to guarantee AS conversion
// compiles (AS1 = flat addr; AS3 = low 32 bits of shared aperture addr).
DEV void dma16(const u16* g, const u16* lds_base) {
  __builtin_amdgcn_global_load_lds(
      (const __attribute__((address_space(1))) void*)(unsigned long long)g,
      (__attribute__((address_space(3))) void*)(u32)(unsigned long long)lds_base,
      16, 0, 0);
}

// ---------- transpose + bf16 convert: xT[b][n][c] = bf16(x[b][c][n]) ----------
__global__ __launch_bounds__(256) void k_transpose(const float* __restrict__ x,
                                                   u16* __restrict__ xT) {
  __shared__ float tile[32][33];
  int b = blockIdx.z;
  int n0 = blockIdx.x * 32, c0 = blockIdx.y * 32;
  int tx = threadIdx.x & 31, ty = threadIdx.x >> 5;  // 32 x 8
  const float* xb = x + (long)b * C * NN;
#pragma unroll
  for (int r = 0; r < 4; ++r)
    tile[ty + r * 8][tx] = xb[(long)(c0 + ty + r * 8) * NN + n0 + tx];
  __syncthreads();
  u16* xTb = xT + (long)b * NN * C;
#pragma unroll
  for (int r = 0; r < 4; ++r)
    xTb[(long)(n0 + ty + r * 8) * C + c0 + tx] = f2bf(tile[tx][ty + r * 8]);
}

// ---------- fp32 -> bf16 convert, all 4 weights in one launch ----------
__global__ __launch_bounds__(256) void k_cvt4(const float* __restrict__ s0,
                                              const float* __restrict__ s1,
                                              const float* __restrict__ s2,
                                              const float* __restrict__ s3,
                                              u16* __restrict__ d0, u16* __restrict__ d1,
                                              u16* __restrict__ d2, u16* __restrict__ d3) {
  int wsel = blockIdx.y;
  const float* s = wsel == 0 ? s0 : wsel == 1 ? s1 : wsel == 2 ? s2 : s3;
  u16* d = wsel == 0 ? d0 : wsel == 1 ? d1 : wsel == 2 ? d2 : d3;
  int i = blockIdx.x * 256 + threadIdx.x;
  d[i] = f2bf(s[i]);
}

// stage 64 rows x 256 u16 (global row stride 256) into LDS rows of 264 (pad 8)
DEV void stage_tile(const u16* __restrict__ g, u16* lds, int t) {
#pragma unroll
  for (int i = 0; i < 8; ++i) {
    int id = t + i * 256;
    int row = id >> 5, ch = id & 31;
    *reinterpret_cast<float4*>(lds + row * 264 + ch * 8) =
        *reinterpret_cast<const float4*>(g + row * 256 + ch * 8);
  }
}

// ---------- fused q/k/v projection: stage xT tile once, 3 weight passes ----------
// qO,kO: (B,N,C) bf16 (q scaled by C^-0.5 * log2e); vO: (B,C,N) bf16
__global__ __launch_bounds__(256) void k_qkv(
    const u16* __restrict__ xT, const u16* __restrict__ wqb, const u16* __restrict__ wkb,
    const u16* __restrict__ wvb, const float* __restrict__ bq, const float* __restrict__ bk,
    const float* __restrict__ bv, u16* __restrict__ qO, u16* __restrict__ kO,
    u16* __restrict__ vO) {
  __shared__ __align__(16) u16 Ash[64 * 264];
  __shared__ __align__(16) u16 Bsh[64 * 264];
  int t = threadIdx.x, w = t >> 6, lane = t & 63, lr = lane & 15, q = lane >> 4;
  int m0 = blockIdx.x * 64, n0 = blockIdx.y * 64, b = blockIdx.z;
  stage_tile(xT + (long)b * NN * C + (long)m0 * 256, Ash, t);
#pragma unroll 1
  for (int wsel = 0; wsel < 3; ++wsel) {
    const u16* wptr = wsel == 0 ? wqb : wsel == 1 ? wkb : wvb;
    stage_tile(wptr + (long)n0 * 256, Bsh, t);
    __syncthreads();
    v4f acc[4];
#pragma unroll
    for (int nt = 0; nt < 4; ++nt)
#pragma unroll
      for (int r = 0; r < 4; ++r) acc[nt][r] = 0.f;
#pragma unroll
    for (int ks = 0; ks < 8; ++ks) {
      v8bf a = *reinterpret_cast<const v8bf*>(Ash + (w * 16 + lr) * 264 + ks * 32 + q * 8);
#pragma unroll
      for (int nt = 0; nt < 4; ++nt) {
        v8bf bb = *reinterpret_cast<const v8bf*>(Bsh + (nt * 16 + lr) * 264 + ks * 32 + q * 8);
        acc[nt] = __builtin_amdgcn_mfma_f32_16x16x32_bf16(a, bb, acc[nt], 0, 0, 0);
      }
    }
    const float* bias = wsel == 0 ? bq : wsel == 1 ? bk : bv;
#pragma unroll
    for (int nt = 0; nt < 4; ++nt) {
#pragma unroll
      for (int r = 0; r < 4; ++r) {
        int gm = m0 + w * 16 + q * 4 + r;   // voxel
        int gn = n0 + nt * 16 + lr;         // out channel
        float val = acc[nt][r] + bias[gn];
        if (wsel == 0) {
          qO[((long)b * NN + gm) * C + gn] = f2bf(val * (0.0625f * LOG2E));
        } else if (wsel == 1) {
          kO[((long)b * NN + gm) * C + gn] = f2bf(val);
        } else {
          vO[(long)b * C * NN + (long)gn * NN + gm] = f2bf(val);
        }
      }
    }
    __syncthreads();  // all Bsh reads done before next restage
  }
}

// ---------- generic C[m,n'] = scale*(sum_k A[m,k]B[n',k] + bias) (+resid) ----------
__global__ __launch_bounds__(256) void k_gemm(
    const u16* __restrict__ A, long aStr, const u16* __restrict__ Bm, long bStr,
    const float* __restrict__ biasM, const float* __restrict__ biasN,
    const float* __restrict__ resid, long rStr, float scale,
    float* __restrict__ outF, u16* __restrict__ outH, long oStr, int ldm, int ldn) {
  __shared__ __align__(16) u16 Ash[64 * 264];
  __shared__ __align__(16) u16 Bsh[64 * 264];
  int t = threadIdx.x;
  int w = t >> 6, lane = t & 63, lr = lane & 15, q = lane >> 4;
  int m0 = blockIdx.x * 64, n0 = blockIdx.y * 64, b = blockIdx.z;
  stage_tile(A + b * aStr + (long)m0 * 256, Ash, t);
  stage_tile(Bm + b * bStr + (long)n0 * 256, Bsh, t);
  __syncthreads();
  v4f acc[4];
#pragma unroll
  for (int nt = 0; nt < 4; ++nt)
#pragma unroll
    for (int r = 0; r < 4; ++r) acc[nt][r] = 0.f;
#pragma unroll
  for (int ks = 0; ks < 8; ++ks) {
    v8bf a = *reinterpret_cast<const v8bf*>(Ash + (w * 16 + lr) * 264 + ks * 32 + q * 8);
#pragma unroll
    for (int nt = 0; nt < 4; ++nt) {
      v8bf bb = *reinterpret_cast<const v8bf*>(Bsh + (nt * 16 + lr) * 264 + ks * 32 + q * 8);
      acc[nt] = __builtin_amdgcn_mfma_f32_16x16x32_bf16(a, bb, acc[nt], 0, 0, 0);
    }
  }
#pragma unroll
  for (int nt = 0; nt < 4; ++nt) {
#pragma unroll
    for (int r = 0; r < 4; ++r) {
      int gm = m0 + w * 16 + q * 4 + r;
      int gn = n0 + nt * 16 + lr;
      float val = acc[nt][r];
      if (biasM) val += biasM[gm];
      if (biasN) val += biasN[gn];
      val *= scale;
      long addr = b * oStr + (long)gm * ldm + (long)gn * ldn;
      if (resid) val += resid[b * rStr + (long)gm * ldm + (long)gn * ldn];
      if (outF) outF[addr] = val;
      else outH[addr] = f2bf(val);
    }
  }
}

// ---------- flash attention, split-j 2-way, log2-domain softmax ----------
// qT,kT: (B,N,C) bf16 (q pre-scaled by C^-0.5*log2e); V: (B,C,N) bf16
// op0/op1: (B,N,C) bf16 normalized partials; ml: (2,B,N,2) fp32 {m,l}
__global__ __launch_bounds__(256) void k_flash(const u16* __restrict__ qT,
                                               const u16* __restrict__ kT,
                                               const u16* __restrict__ V,
                                               u16* __restrict__ op0,
                                               u16* __restrict__ op1,
                                               float* __restrict__ ml) {
  __shared__ __align__(16) u16 ksh[64 * 256];   // 64 j-rows x 32 chunks, XOR-swizzled
  __shared__ __align__(16) u16 vsh[256 * 64];   // 256 c-rows x 8 chunks, XOR-swizzled
  __shared__ __align__(16) u16 psh[4 * 16 * 72];
  int t = threadIdx.x;
  int w = t >> 6, lane = t & 63, lr = lane & 15, q = lane >> 4;
  int b = blockIdx.z, h = blockIdx.y;
  int i0 = blockIdx.x * 64;
  const u16* qb = qT + ((long)b * NN + i0 + w * 16) * C;
  const u16* kb = kT + (long)b * NN * C;
  const u16* vb = V + (long)b * C * NN;

  v8bf qf[8];
#pragma unroll
  for (int ks = 0; ks < 8; ++ks)
    qf[ks] = *reinterpret_cast<const v8bf*>(qb + lr * C + ks * 32 + q * 8);

  v4f accO[16];
#pragma unroll
  for (int ct = 0; ct < 16; ++ct)
#pragma unroll
    for (int r = 0; r < 4; ++r) accO[ct][r] = 0.f;
  float mst[4], lst[4];
#pragma unroll
  for (int r = 0; r < 4; ++r) { mst[r] = -3.0e38f; lst[r] = 0.f; }

  u16* pw = psh + w * (16 * 72);
  const int wi = w * 8;
  const int xl = lr & 7;  // XOR swizzle key for fragment reads

  for (int it = 0; it < 32; ++it) {
    int j0 = h * 2048 + it * 64;
    __syncthreads();  // prev iter's LDS reads done before DMA overwrite
#pragma unroll
    for (int i = 0; i < 8; ++i) {
      int idx = wi + i;
      int kr = idx * 2 + (lane >> 5);
      int kc = (lane & 31) ^ (kr & 7);
      dma16(kb + (long)(j0 + kr) * 256 + kc * 8, ksh + idx * 512);
      int vr = idx * 8 + (lane >> 3);
      int vc = (lane & 7) ^ (vr & 7);
      dma16(vb + (long)vr * NN + j0 + vc * 8, vsh + idx * 512);
    }
    __syncthreads();  // drain DMA (vmcnt) + barrier

    v4f s[4];
#pragma unroll
    for (int jt = 0; jt < 4; ++jt)
#pragma unroll
      for (int r = 0; r < 4; ++r) s[jt][r] = 0.f;
#pragma unroll
    for (int ks = 0; ks < 8; ++ks) {
#pragma unroll
      for (int jt = 0; jt < 4; ++jt) {
        v8bf kf = *reinterpret_cast<const v8bf*>(
            ksh + (jt * 16 + lr) * 256 + (((ks * 4 + q) ^ xl) << 3));
        s[jt] = __builtin_amdgcn_mfma_f32_16x16x32_bf16(qf[ks], kf, s[jt], 0, 0, 0);
      }
    }

    // online softmax in log2 domain (scale*log2e folded into q)
    float al[4];
#pragma unroll
    for (int r = 0; r < 4; ++r) {
      float mx = fmaxf(fmaxf(s[0][r], s[1][r]), fmaxf(s[2][r], s[3][r]));
#pragma unroll
      for (int d = 1; d < 16; d <<= 1) mx = fmaxf(mx, __shfl_xor(mx, d, 64));
      float mn = fmaxf(mst[r], mx);
      al[r] = exp2f(mst[r] - mn);
      mst[r] = mn;
    }
#pragma unroll
    for (int r = 0; r < 4; ++r) {
      float rs = 0.f;
#pragma unroll
      for (int jt = 0; jt < 4; ++jt) {
        float p = exp2f(s[jt][r] - mst[r]);
        s[jt][r] = p;
        rs += p;
      }
#pragma unroll
      for (int d = 1; d < 16; d <<= 1) rs += __shfl_xor(rs, d, 64);
      lst[r] = lst[r] * al[r] + rs;
    }
#pragma unroll
    for (int ct = 0; ct < 16; ++ct)
#pragma unroll
      for (int r = 0; r < 4; ++r) accO[ct][r] *= al[r];

    // P: C/D layout -> LDS -> A layout (per-wave region)
#pragma unroll
    for (int jt = 0; jt < 4; ++jt)
#pragma unroll
      for (int r = 0; r < 4; ++r)
        pw[(q * 4 + r) * 72 + jt * 16 + lr] = f2bf(s[jt][r]);
    __syncthreads();

    v8bf pa0 = *reinterpret_cast<const v8bf*>(pw + lr * 72 + q * 8);
    v8bf pa1 = *reinterpret_cast<const v8bf*>(pw + lr * 72 + 32 + q * 8);
    int x0 = (q ^ xl) << 3;
    int x1 = ((q + 4) ^ xl) << 3;
#pragma unroll
    for (int ct = 0; ct < 16; ++ct) {
      int row = (ct * 16 + lr) * 64;
      v8bf v0 = *reinterpret_cast<const v8bf*>(vsh + row + x0);
      accO[ct] = __builtin_amdgcn_mfma_f32_16x16x32_bf16(pa0, v0, accO[ct], 0, 0, 0);
      v8bf v1 = *reinterpret_cast<const v8bf*>(vsh + row + x1);
      accO[ct] = __builtin_amdgcn_mfma_f32_16x16x32_bf16(pa1, v1, accO[ct], 0, 0, 0);
    }
  }

  float inv[4];
#pragma unroll
  for (int r = 0; r < 4; ++r) inv[r] = 1.0f / lst[r];
  u16* ob = (h == 0 ? op0 : op1) + ((long)b * NN + i0 + w * 16) * C;
#pragma unroll
  for (int ct = 0; ct < 16; ++ct)
#pragma unroll
    for (int r = 0; r < 4; ++r)
      ob[(q * 4 + r) * C + ct * 16 + lr] = f2bf(accO[ct][r] * inv[r]);
  if (lr == 0) {
    long rbase = ((long)h * CB + b) * NN + i0 + w * 16 + q * 4;
#pragma unroll
    for (int r = 0; r < 4; ++r) {
      ml[(rbase + r) * 2] = mst[r];
      ml[(rbase + r) * 2 + 1] = lst[r];
    }
  }
}

// ---------- merge the two j-half partials ----------
__global__ __launch_bounds__(256) void k_combine(const u16* __restrict__ o1p,
                                                 const u16* __restrict__ o2p,
                                                 const float* __restrict__ ml,
                                                 u16* __restrict__ o) {
  long row = (long)blockIdx.x * 8 + (threadIdx.x >> 5);
  int tc = (threadIdx.x & 31) * 8;
  float m1 = ml[row * 2], l1 = ml[row * 2 + 1];
  long row2 = (long)CB * NN + row;
  float m2 = ml[row2 * 2], l2 = ml[row2 * 2 + 1];
  float mx = fmaxf(m1, m2);
  float a1 = exp2f(m1 - mx) * l1, a2 = exp2f(m2 - mx) * l2;
  float inv = 1.f / (a1 + a2);
  a1 *= inv; a2 *= inv;
  uint4 u1 = *reinterpret_cast<const uint4*>(o1p + row * C + tc);
  uint4 u2 = *reinterpret_cast<const uint4*>(o2p + row * C + tc);
  const u16* p1 = reinterpret_cast<const u16*>(&u1);
  const u16* p2 = reinterpret_cast<const u16*>(&u2);
  u16 outv[8];
#pragma unroll
  for (int i = 0; i < 8; ++i) outv[i] = f2bf(a1 * bf2f(p1[i]) + a2 * bf2f(p2[i]));
  *reinterpret_cast<uint4*>(o + row * C + tc) = *reinterpret_cast<const uint4*>(outv);
}

extern "C" void kernel_launch(void* const* d_in, const int* in_sizes, int n_in,
                              void* d_out, int out_size, void* d_ws, size_t ws_size,
                              hipStream_t stream) {
  const float* x = (const float*)d_in[0];
  const float* wq = (const float*)d_in[1];
  const float* bq = (const float*)d_in[2];
  const float* wk = (const float*)d_in[3];
  const float* bk = (const float*)d_in[4];
  const float* wv = (const float*)d_in[5];
  const float* bv = (const float*)d_in[6];
  const float* wp = (const float*)d_in[7];
  const float* bp = (const float*)d_in[8];
  float* out = (float*)d_out;
  char* ws = (char*)d_ws;

  // ws: 4 weights bf16 (512KB), 5 x 8MB bf16 slots, 256KB ml
  u16* wqb = (u16*)(ws + 0);
  u16* wkb = (u16*)(ws + 131072L);
  u16* wvb = (u16*)(ws + 262144L);
  u16* wpb = (u16*)(ws + 393216L);
  u16* xT  = (u16*)(ws + 524288L);                    // slot1: xT, later opart0
  u16* qTw = (u16*)(ws + 524288L + 1 * 8388608L);     // slot2: q, later combined O
  u16* kTw = (u16*)(ws + 524288L + 2 * 8388608L);     // slot3: k
  u16* vw  = (u16*)(ws + 524288L + 3 * 8388608L);     // slot4: v
  u16* op1 = (u16*)(ws + 524288L + 4 * 8388608L);     // slot5: opart1
  float* ml = (float*)(ws + 524288L + 5 * 8388608L);  // 256KB
  u16* op0 = xT;    // xT dead after k_qkv
  u16* oW  = qTw;   // q dead after k_flash

  k_cvt4<<<dim3(256, 4), 256, 0, stream>>>(wq, wk, wv, wp, wqb, wkb, wvb, wpb);
  k_transpose<<<dim3(128, 8, CB), 256, 0, stream>>>(x, xT);
  k_qkv<<<dim3(64, 4, CB), 256, 0, stream>>>(xT, wqb, wkb, wvb, bq, bk, bv, qTw, kTw, vw);
  k_flash<<<dim3(64, 2, CB), 256, 0, stream>>>(qTw, kTw, vw, op0, op1, ml);
  k_combine<<<2048, 256, 0, stream>>>(op0, op1, ml, oW);

  long nc = (long)NN * C;
  // out[b][o][n] = wp . attn + bp + x
  k_gemm<<<dim3(4, 64, CB), 256, 0, stream>>>(wpb, 0, oW, nc, bp, nullptr, x, nc,
                                              1.0f, out, nullptr, nc, NN, 1);
}